// Round 7
// baseline (941.567 us; speedup 1.0000x reference)
//
#include <hip/hip_runtime.h>

// EncoderBlock: B=4 S=2048 D=1024 H=16 DK=64 DFF=4096
// R7: attention rebuilt on mfma_f32_32x32x16_bf16 — 4 waves x 32 q-rows
//     (256 thr), halves per-block LDS K/V fragment duplication (DS-pipe was
//     the measured bottleneck). Same 32KB LDS -> all 1024 blocks co-resident.

typedef unsigned short u16;
typedef __bf16 bf16x8 __attribute__((ext_vector_type(8)));
typedef float f32x4 __attribute__((ext_vector_type(4)));
typedef float f32x16 __attribute__((ext_vector_type(16)));

typedef __attribute__((address_space(1))) const void* as1_cvp;
typedef __attribute__((address_space(3))) void* as3_vp;

__device__ __forceinline__ void async_copy16(const void* g, void* l) {
  __builtin_amdgcn_global_load_lds((as1_cvp)g, (as3_vp)l, 16, 0, 0);
}

__device__ __forceinline__ u16 f2bf(float f) {
  unsigned u = __float_as_uint(f);
  u += 0x7fffu + ((u >> 16) & 1u);  // RNE
  return (u16)(u >> 16);
}

__device__ __forceinline__ float fast_exp2(float x) {
  return __builtin_amdgcn_exp2f(x);
}

// ---------- transpose fp32 [K,N] -> bf16 [N,K], optional scale ----------
__global__ __launch_bounds__(256) void k_transpose_bf16(
    const float* __restrict__ src, u16* __restrict__ dst, int K, int N,
    float scale) {
  __shared__ float tile[32][33];
  int n0 = blockIdx.x * 32, k0 = blockIdx.y * 32;
  int c = threadIdx.x & 31, r0 = threadIdx.x >> 5;
#pragma unroll
  for (int i = 0; i < 32; i += 8)
    tile[r0 + i][c] = src[(size_t)(k0 + r0 + i) * N + n0 + c];
  __syncthreads();
#pragma unroll
  for (int i = 0; i < 32; i += 8)
    dst[(size_t)(n0 + r0 + i) * K + k0 + c] = f2bf(tile[c][r0 + i] * scale);
}

// ---------- pack QKV bias (bq scaled) ----------
__global__ __launch_bounds__(256) void k_pack_bias(
    const float* __restrict__ bq, const float* __restrict__ bk,
    const float* __restrict__ bv, float* __restrict__ out, float qscale) {
  int i = blockIdx.x * 256 + threadIdx.x;
  float v;
  if (i < 1024) v = bq[i] * qscale;
  else if (i < 2048) v = bk[i - 1024];
  else v = bv[i - 2048];
  out[i] = v;
}

// ---------- layernorm (ddof=1, /(std+eps)) -> bf16 ----------
__global__ __launch_bounds__(256) void k_layernorm_bf16(
    const float* __restrict__ x, const float* __restrict__ w,
    const float* __restrict__ b, u16* __restrict__ out) {
  const int D = 1024;
  int row = blockIdx.x, tid = threadIdx.x;
  const float4* xr = (const float4*)(x + (size_t)row * D);
  float4 v = xr[tid];
  float s = v.x + v.y + v.z + v.w;
  float ss = v.x * v.x + v.y * v.y + v.z * v.z + v.w * v.w;
#pragma unroll
  for (int off = 1; off < 64; off <<= 1) {
    s += __shfl_xor(s, off);
    ss += __shfl_xor(ss, off);
  }
  __shared__ float rs[4], rss[4];
  int wave = tid >> 6, lane = tid & 63;
  if (lane == 0) { rs[wave] = s; rss[wave] = ss; }
  __syncthreads();
  float S_ = rs[0] + rs[1] + rs[2] + rs[3];
  float SS = rss[0] + rss[1] + rss[2] + rss[3];
  float mean = S_ * (1.0f / D);
  float var = (SS - (float)D * mean * mean) * (1.0f / (D - 1));
  float inv = 1.0f / (sqrtf(fmaxf(var, 0.0f)) + 1e-6f);
  float4 wv = ((const float4*)w)[tid], bv = ((const float4*)b)[tid];
  u16* orow = out + (size_t)row * D + tid * 4;
  orow[0] = f2bf(wv.x * (v.x - mean) * inv + bv.x);
  orow[1] = f2bf(wv.y * (v.y - mean) * inv + bv.y);
  orow[2] = f2bf(wv.z * (v.z - mean) * inv + bv.z);
  orow[3] = f2bf(wv.w * (v.w - mean) * inv + bv.w);
}

// ---------- GEMM: C[M,N] = A[M,K]bf16 @ Bt[N,K]^T + bias (+res)(relu) ----------
template <bool RELU, bool HAS_RES, bool OUT_BF16>
__global__ __launch_bounds__(256) void k_gemm(
    const u16* __restrict__ A, const u16* __restrict__ Bt,
    const float* __restrict__ bias, const float* __restrict__ res,
    void* __restrict__ outp, int M, int N, int K) {
  __shared__ __align__(16) u16 As[128 * 32];
  __shared__ __align__(16) u16 Bs[128 * 32];
  const int tid = threadIdx.x;
  const int lane = tid & 63, wave = tid >> 6;
  const int quad = lane >> 4, l16 = lane & 15;
  const int m0 = blockIdx.y * 128, n0 = blockIdx.x * 128;
  const int wm = (wave >> 1) * 64, wn = (wave & 1) * 64;

  const int r0 = tid >> 2, o0 = (tid & 3) * 8;
  const u16* a0 = A + (size_t)(m0 + r0) * K + o0;
  const u16* a1 = A + (size_t)(m0 + r0 + 64) * K + o0;
  const u16* b0p = Bt + (size_t)(n0 + r0) * K + o0;
  const u16* b1p = Bt + (size_t)(n0 + r0 + 64) * K + o0;
  u16* lA0 = As + tid * 8;  u16* lA1 = As + (tid + 256) * 8;
  u16* lB0 = Bs + tid * 8;  u16* lB1 = Bs + (tid + 256) * 8;

  f32x4 zero = {0.0f, 0.0f, 0.0f, 0.0f};
  f32x4 acc[4][4];
#pragma unroll
  for (int i = 0; i < 4; i++)
#pragma unroll
    for (int j = 0; j < 4; j++) acc[i][j] = zero;

  for (int k0 = 0; k0 < K; k0 += 32) {
    __syncthreads();
    async_copy16(a0 + k0, lA0);
    async_copy16(a1 + k0, lA1);
    async_copy16(b0p + k0, lB0);
    async_copy16(b1p + k0, lB1);
    __syncthreads();
    bf16x8 af[4], bfr[4];
#pragma unroll
    for (int mb = 0; mb < 4; mb++)
      af[mb] = *(const bf16x8*)&As[(wm + mb * 16 + l16) * 32 + quad * 8];
#pragma unroll
    for (int nb = 0; nb < 4; nb++)
      bfr[nb] = *(const bf16x8*)&Bs[(wn + nb * 16 + l16) * 32 + quad * 8];
#pragma unroll
    for (int mb = 0; mb < 4; mb++)
#pragma unroll
      for (int nb = 0; nb < 4; nb++)
        acc[mb][nb] = __builtin_amdgcn_mfma_f32_16x16x32_bf16(
            af[mb], bfr[nb], acc[mb][nb], 0, 0, 0);
  }
#pragma unroll
  for (int mb = 0; mb < 4; mb++) {
#pragma unroll
    for (int nb = 0; nb < 4; nb++) {
      int col = n0 + wn + nb * 16 + l16;
      float bb = bias[col];
#pragma unroll
      for (int r = 0; r < 4; r++) {
        int row = m0 + wm + mb * 16 + quad * 4 + r;
        float vv = acc[mb][nb][r] + bb;
        if (HAS_RES) vv += res[(size_t)row * N + col];
        if (RELU) vv = fmaxf(vv, 0.0f);
        if (OUT_BF16) ((u16*)outp)[(size_t)row * N + col] = f2bf(vv);
        else ((float*)outp)[(size_t)row * N + col] = vv;
      }
    }
  }
}

// ---------- flash attention, 256 threads, 4 waves x 32 q-rows, 32x32x16 ----
// qkv: fused [8192][3072] bf16 (q|k|v); q pre-scaled by log2(e)/sqrt(dk).
// Max-free exp2 softmax; row-sum via ones-MFMA.
// 32x32 layouts: A[m=lane&31][k=(lane>>5)*8+j]; B mirrors; C/D col=lane&31,
// row=(reg&3)+8*(reg>>2)+4*(lane>>5)  [m74/m101].
// Swizzles: Q/K chunk-XOR o'=o^(row&7); P rotation key'=(key+row*8)&63;
// V^T rotation key'=(key+16*g+8)&63, g=(dk>>3)&7.
__global__ __launch_bounds__(256, 4) void k_attention(
    const u16* __restrict__ qkv, const int* __restrict__ mask,
    u16* __restrict__ out) {
  const int S = 2048, D = 1024, QS = 3072;
  int blk = blockIdx.x;
  int qt = blk & 15, h = (blk >> 4) & 15, bb = blk >> 8;
  int tid = threadIdx.x, lane = tid & 63, wave = tid >> 6;
  int m = lane & 31, hh = lane >> 5;

  __shared__ __align__(16) u16 Qs[128 * 64];  // becomes P after frag reads
  __shared__ __align__(16) u16 Ks[64 * 64];
  __shared__ __align__(16) u16 Vs[64 * 64];   // V^T, rotated

  const int qrowbase = bb * S + qt * 128;
  const int sbase = bb * S;
  // Q DMA: 4 chunks/thread
#pragma unroll
  for (int i = 0; i < 4; i++) {
    int c = tid + i * 256, r = c >> 3, o = ((c & 7) ^ (r & 7)) * 8;
    async_copy16(qkv + (size_t)(qrowbase + r) * QS + h * 64 + o, Qs + c * 8);
  }
  __syncthreads();
  // Q A-frags (row qr, k = ks*16 + hh*8 + j)
  const int qr = wave * 32 + m;
  bf16x8 aq[4];
#pragma unroll
  for (int ks = 0; ks < 4; ks++) {
    int c = ks * 2 + hh;
    aq[ks] = *(const bf16x8*)&Qs[qr * 64 + ((c ^ (m & 7)) * 8)];
  }

  bf16x8 ones;
  {
    union { u16 s[8]; bf16x8 v; } o_;
#pragma unroll
    for (int j = 0; j < 8; j++) o_.s[j] = 0x3F80;  // bf16 1.0
    ones = o_.v;
  }

  f32x16 acc0, acc1, lr;
#pragma unroll
  for (int i = 0; i < 16; i++) { acc0[i] = 0.0f; acc1[i] = 0.0f; lr[i] = 0.0f; }

  // staging patterns
  const int kc0 = tid, kr0 = kc0 >> 3, ko0 = ((kc0 & 7) ^ (kr0 & 7)) * 8;
  const int kc1 = tid + 256, kr1 = kc1 >> 3, ko1 = ((kc1 & 7) ^ (kr1 & 7)) * 8;
  const int vkey = tid >> 2, vdk0 = (tid & 3) * 16;
  u16* Ps = Qs + wave * 2048;

  for (int kt = 0; kt < 32; kt++) {
    __syncthreads();  // WAR: previous iteration's readers done
    const int kb0 = sbase + kt * 64;
    async_copy16(qkv + (size_t)(kb0 + kr0) * QS + 1024 + h * 64 + ko0,
                 Ks + kc0 * 8);
    async_copy16(qkv + (size_t)(kb0 + kr1) * QS + 1024 + h * 64 + ko1,
                 Ks + kc1 * 8);
    {  // V^T staging: 16-wide load, 16 rotated scalar stores
      union { uint4 u[2]; u16 s[16]; } t;
      const u16* vp = qkv + (size_t)(kb0 + vkey) * QS + 2048 + h * 64 + vdk0;
      t.u[0] = *(const uint4*)vp;
      t.u[1] = *(const uint4*)(vp + 8);
#pragma unroll
      for (int j = 0; j < 16; j++) {
        int dk = vdk0 + j, g = (dk >> 3) & 7;
        Vs[dk * 64 + ((vkey + 16 * g + 8) & 63)] = t.s[j];
      }
    }
    int mc0 = mask[kb0 + m], mc1 = mask[kb0 + 32 + m];
    __syncthreads();  // drain K-DMA + V stores
    // ---- S 32x64 per wave = Q @ K^T ----
    f32x16 s0, s1;
#pragma unroll
    for (int i = 0; i < 16; i++) { s0[i] = 0.0f; s1[i] = 0.0f; }
#pragma unroll
    for (int ks = 0; ks < 4; ks++) {
      int c = ks * 2 + hh;
      bf16x8 kf0 = *(const bf16x8*)&Ks[m * 64 + ((c ^ (m & 7)) * 8)];
      bf16x8 kf1 = *(const bf16x8*)&Ks[(32 + m) * 64 + ((c ^ (m & 7)) * 8)];
      s0 = __builtin_amdgcn_mfma_f32_32x32x16_bf16(aq[ks], kf0, s0, 0, 0, 0);
      s1 = __builtin_amdgcn_mfma_f32_32x32x16_bf16(aq[ks], kf1, s1, 0, 0, 0);
    }
    // ---- max-free softmax numerator ----
#pragma unroll
    for (int i = 0; i < 16; i++) {
      float p0 = fast_exp2(s0[i]);
      float p1 = fast_exp2(s1[i]);
      s0[i] = mc0 ? p0 : 0.0f;
      s1[i] = mc1 ? p1 : 0.0f;
    }
    // ---- P: C-layout -> LDS (wave-private, rotated) ----
#pragma unroll
    for (int reg = 0; reg < 16; reg++) {
      int rl = (reg & 3) + 8 * (reg >> 2) + 4 * hh;
      Ps[rl * 64 + ((m + rl * 8) & 63)] = f2bf(s0[reg]);
      Ps[rl * 64 + ((32 + m + rl * 8) & 63)] = f2bf(s1[reg]);
    }
    // ---- P A-frags ----
    bf16x8 ap[4];
#pragma unroll
    for (int ks = 0; ks < 4; ks++) {
      int st = (ks * 16 + hh * 8 + m * 8) & 63;
      ap[ks] = *(const bf16x8*)&Ps[m * 64 + st];
    }
    // ---- row-sum via ones-MFMA ----
    f32x16 zs;
#pragma unroll
    for (int i = 0; i < 16; i++) zs[i] = 0.0f;
#pragma unroll
    for (int ks = 0; ks < 4; ks++)
      zs = __builtin_amdgcn_mfma_f32_32x32x16_bf16(ap[ks], ones, zs, 0, 0, 0);
    // ---- PV ----
    const int g0 = m >> 3, g1 = 4 + (m >> 3);
#pragma unroll
    for (int ks = 0; ks < 4; ks++) {
      int kbase = ks * 16 + hh * 8;
      bf16x8 v0 = *(const bf16x8*)&Vs[m * 64 + ((kbase + 16 * g0 + 8) & 63)];
      bf16x8 v1 =
          *(const bf16x8*)&Vs[(32 + m) * 64 + ((kbase + 16 * g1 + 8) & 63)];
      acc0 = __builtin_amdgcn_mfma_f32_32x32x16_bf16(ap[ks], v0, acc0, 0, 0, 0);
      acc1 = __builtin_amdgcn_mfma_f32_32x32x16_bf16(ap[ks], v1, acc1, 0, 0, 0);
    }
#pragma unroll
    for (int i = 0; i < 16; i++) lr[i] += zs[i];
  }
  // ---- epilogue ----
#pragma unroll
  for (int reg = 0; reg < 16; reg++) {
    int rl = (reg & 3) + 8 * (reg >> 2) + 4 * hh;
    float inv = 1.0f / lr[reg];
    size_t rowoff = (size_t)(qrowbase + wave * 32 + rl) * D + h * 64;
    out[rowoff + m] = f2bf(acc0[reg] * inv);
    out[rowoff + 32 + m] = f2bf(acc1[reg] * inv);
  }
}

extern "C" void kernel_launch(void* const* d_in, const int* in_sizes, int n_in,
                              void* d_out, int out_size, void* d_ws,
                              size_t ws_size, hipStream_t stream) {
  const float* x    = (const float*)d_in[0];
  const int*   mask = (const int*)d_in[1];
  const float* wq = (const float*)d_in[2];   const float* bq = (const float*)d_in[3];
  const float* wk = (const float*)d_in[4];   const float* bk = (const float*)d_in[5];
  const float* wv = (const float*)d_in[6];   const float* bv = (const float*)d_in[7];
  const float* wo = (const float*)d_in[8];   const float* bo = (const float*)d_in[9];
  const float* w1 = (const float*)d_in[10];  const float* b1 = (const float*)d_in[11];
  const float* w2 = (const float*)d_in[12];  const float* b2 = (const float*)d_in[13];
  const float* ln1w = (const float*)d_in[14]; const float* ln1b = (const float*)d_in[15];
  const float* ln2w = (const float*)d_in[16]; const float* ln2b = (const float*)d_in[17];
  float* outp = (float*)d_out;

  char* ws = (char*)d_ws;
  const size_t MB = 1024 * 1024;
  u16* wqkvT = (u16*)(ws + 0 * MB);
  u16* woT   = (u16*)(ws + 6 * MB);
  u16* w1T   = (u16*)(ws + 8 * MB);
  u16* w2T   = (u16*)(ws + 16 * MB);
  u16* xn    = (u16*)(ws + 24 * MB);
  u16* qkvb  = (u16*)(ws + 40 * MB);
  u16* hb    = (u16*)(ws + 40 * MB);   // alias (qkv dead by ffn1)
  float* bqkv = (float*)(ws + 88 * MB);
  float* y1  = (float*)(ws + 104 * MB);

  const float qscale = 0.125f * 1.44269504f;  // log2(e)/sqrt(DK)

  k_transpose_bf16<<<dim3(32, 32), 256, 0, stream>>>(wq, wqkvT, 1024, 1024, qscale);
  k_transpose_bf16<<<dim3(32, 32), 256, 0, stream>>>(wk, wqkvT + 1024 * 1024, 1024, 1024, 1.0f);
  k_transpose_bf16<<<dim3(32, 32), 256, 0, stream>>>(wv, wqkvT + 2048 * 1024, 1024, 1024, 1.0f);
  k_transpose_bf16<<<dim3(32, 32), 256, 0, stream>>>(wo, woT, 1024, 1024, 1.0f);
  k_transpose_bf16<<<dim3(128, 32), 256, 0, stream>>>(w1, w1T, 1024, 4096, 1.0f);
  k_transpose_bf16<<<dim3(32, 128), 256, 0, stream>>>(w2, w2T, 4096, 1024, 1.0f);
  k_pack_bias<<<12, 256, 0, stream>>>(bq, bk, bv, bqkv, qscale);

  k_layernorm_bf16<<<8192, 256, 0, stream>>>(x, ln1w, ln1b, xn);

  k_gemm<false, false, true><<<dim3(24, 64), 256, 0, stream>>>(
      xn, wqkvT, bqkv, nullptr, qkvb, 8192, 3072, 1024);

  k_attention<<<1024, 256, 0, stream>>>(qkvb, mask, xn);

  dim3 g1(8, 64);
  k_gemm<false, true, false><<<g1, 256, 0, stream>>>(xn, woT, bo, x, y1, 8192, 1024, 1024);

  k_layernorm_bf16<<<8192, 256, 0, stream>>>(y1, ln2w, ln2b, xn);

  k_gemm<true, false, true><<<dim3(32, 64), 256, 0, stream>>>(
      xn, w1T, b1, nullptr, hb, 8192, 4096, 1024);

  k_gemm<false, true, false><<<g1, 256, 0, stream>>>(hb, w2T, b2, y1, outp, 8192, 1024, 4096);
}